// Round 6
// baseline (516.234 us; speedup 1.0000x reference)
//
#include <hip/hip_runtime.h>
#include <type_traits>

#define N_NODES 50000

using short8  = __attribute__((ext_vector_type(8))) short;
using floatx4 = __attribute__((ext_vector_type(4))) float;
using f32x2   = __attribute__((ext_vector_type(2))) float;

__device__ inline unsigned short f2b(float f) {
    unsigned u = __float_as_uint(f);
    u += 0x7FFFu + ((u >> 16) & 1u);           // RNE
    return (unsigned short)(u >> 16);
}
__device__ inline float b2f(unsigned short h) {
    return __uint_as_float(((unsigned)h) << 16);
}

// packed f32 FMA (VOP3P, all operands 64-bit pairs).
// pk_fma_lo: d.{lo,hi} = a.lo * b.{lo,hi} + c.{lo,hi}
__device__ inline f32x2 pk_fma_lo(f32x2 a, f32x2 b, f32x2 c) {
    f32x2 d;
    asm("v_pk_fma_f32 %0, %1, %2, %3 op_sel_hi:[0,1,1]"
        : "=v"(d) : "v"(a), "v"(b), "v"(c));
    return d;
}
// pk_fma_hi: d.{lo,hi} = a.hi * b.{lo,hi} + c.{lo,hi}
__device__ inline f32x2 pk_fma_hi(f32x2 a, f32x2 b, f32x2 c) {
    f32x2 d;
    asm("v_pk_fma_f32 %0, %1, %2, %3 op_sel:[1,0,0] op_sel_hi:[1,1,1]"
        : "=v"(d) : "v"(a), "v"(b), "v"(c));
    return d;
}
__device__ inline f32x2 pk_add(f32x2 a, f32x2 b) {
    f32x2 d;
    asm("v_pk_add_f32 %0, %1, %2" : "=v"(d) : "v"(a), "v"(b));
    return d;
}

// ---------------------------------------------------------------------------
// CSR build
// ---------------------------------------------------------------------------
__global__ __launch_bounds__(256) void zero_int_kernel(int* __restrict__ p, int n)
{
    int i = blockIdx.x * 256 + threadIdx.x;
    if (i < n) p[i] = 0;
}

__global__ __launch_bounds__(256) void hist_kernel(const int* __restrict__ dstv,
                                                   int* __restrict__ cnt, int E)
{
    int e = blockIdx.x * 256 + threadIdx.x;
    if (e < E) atomicAdd(&cnt[dstv[e]], 1);
}

__global__ __launch_bounds__(256) void scanA_kernel(const int* __restrict__ cnt,
                                                    int* __restrict__ row_start,
                                                    int* __restrict__ bsum, int n)
{
    __shared__ int s[256];
    int t = threadIdx.x;
    int i = blockIdx.x * 256 + t;
    int val = (i < n) ? cnt[i] : 0;
    s[t] = val;
    __syncthreads();
#pragma unroll
    for (int off = 1; off < 256; off <<= 1) {
        int v = (t >= off) ? s[t - off] : 0;
        __syncthreads();
        s[t] += v;
        __syncthreads();
    }
    if (i < n) row_start[i] = s[t] - val;
    if (t == 255) bsum[blockIdx.x] = s[255];
}

__global__ __launch_bounds__(256) void scanB_kernel(int* __restrict__ bsum, int nb)
{
    __shared__ int s[256];
    int t = threadIdx.x;
    int val = (t < nb) ? bsum[t] : 0;
    s[t] = val;
    __syncthreads();
#pragma unroll
    for (int off = 1; off < 256; off <<= 1) {
        int v = (t >= off) ? s[t - off] : 0;
        __syncthreads();
        s[t] += v;
        __syncthreads();
    }
    if (t < nb) bsum[t] = s[t] - val;
}

__global__ __launch_bounds__(256) void scanC_kernel(int* __restrict__ row_start,
                                                    int* __restrict__ woff,
                                                    const int* __restrict__ bsum, int n)
{
    int i = blockIdx.x * 256 + threadIdx.x;
    if (i < n) {
        int v = row_start[i] + bsum[blockIdx.x];
        row_start[i] = v;
        woff[i] = v;
    }
}

__global__ __launch_bounds__(256) void scatter_kernel(const int* __restrict__ srcv,
                                                      const int* __restrict__ dstv,
                                                      int* __restrict__ woff,
                                                      int2* __restrict__ sorted2, int E)
{
    int e = blockIdx.x * 256 + threadIdx.x;
    if (e < E) {
        int pos = atomicAdd(&woff[dstv[e]], 1);
        sorted2[pos] = make_int2(srcv[e], e);
    }
}

// ---------------------------------------------------------------------------
// Weight cast+transpose: w [K,256] f32 -> wT [256][K] bf16
// ---------------------------------------------------------------------------
__global__ __launch_bounds__(256) void castT_kernel(const float* __restrict__ w,
                                                    unsigned short* __restrict__ out, int K)
{
    int i = blockIdx.x * 256 + threadIdx.x;
    if (i < K * 256) {
        int k = i >> 8, c = i & 255;
        out[c * K + k] = f2b(w[i]);
    }
}

// ---------------------------------------------------------------------------
// Gather aggregation, one wave per node (round-0 topology: best measured).
//
// ROUND-6: ea staged to LDS per 64-edge batch via global_load_lds
// (4 instructions/batch replace 256 per-edge broadcast vector loads),
// issued BEFORE the compute that hides its latency (round 1 issued it
// after + drained immediately = zero overlap, plus a persistent grid that
// collapsed occupancy — both fixed here). Compute reads ea via broadcast
// ds_read_b128 (same-address across lanes = conflict-free, lgkm-counted
// precisely). x row loads stay per-edge coalesced + depth-2 ping-pong:
// now the ONLY vmcnt consumers (5 -> 1 vector-mem ops/edge).
// Arithmetic bit-identical to round 0.
// ---------------------------------------------------------------------------
template<int D, bool XB>
__global__ __launch_bounds__(256) void agg_kernel(
    const float*          __restrict__ xf,
    const unsigned short* __restrict__ xb,
    const float*          __restrict__ ea,     // [E, 16]
    const float*          __restrict__ ew,     // [16, D]
    const float*          __restrict__ ebias,  // [D]
    const int*            __restrict__ row_start,
    const int*            __restrict__ cnt,
    const int2*           __restrict__ sorted2, // [E] {src, eid}
    float*                __restrict__ agg,    // [N, D]
    int N)
{
    constexpr int DPL = D / 64;     // dims per lane
    constexpr int NP  = DPL / 2;    // f32x2 pairs per lane
    using XT = std::conditional_t<XB, ushort4,
               std::conditional_t<DPL == 2, float2, float4>>;

    __shared__ float sEA[4][2][64][16];   // [wave][buf][edge][16 floats] = 32 KiB

    const int lane = threadIdx.x & 63;
    const int w    = threadIdx.x >> 6;
    const int node = blockIdx.x * 4 + w;
    if (node >= N) return;
    const int d0 = lane * DPL;

    f32x2 wrp[16 * NP];
#pragma unroll
    for (int k = 0; k < 16; ++k) {
        if constexpr (NP == 1) {
            float2 w2 = *reinterpret_cast<const float2*>(ew + k * D + d0);
            wrp[k] = f32x2{w2.x, w2.y};
        } else {
            float4 w4 = *reinterpret_cast<const float4*>(ew + k * D + d0);
            wrp[k * 2 + 0] = f32x2{w4.x, w4.y};
            wrp[k * 2 + 1] = f32x2{w4.z, w4.w};
        }
    }
    f32x2 bx[NP];
#pragma unroll
    for (int p = 0; p < NP; ++p)
        bx[p] = f32x2{ebias[d0 + p * 2], ebias[d0 + p * 2 + 1]};

    f32x2 acc[NP];
#pragma unroll
    for (int p = 0; p < NP; ++p) acc[p] = f32x2{0.f, 0.f};

    const int s0 = __builtin_amdgcn_readfirstlane(row_start[node]);
    const int c  = __builtin_amdgcn_readfirstlane(cnt[node]);

    // stage one <=64-edge batch's ea rows into LDS buffer bi.
    // HW writes lane l at ldsbase + l*16B; lane l fetches edge (l>>2),
    // 16B chunk (l&3)  ->  linear [edge][16 float] rows. (rule: linear
    // dest, per-lane global src.)
    auto STAGE = [&](int2 prv, int cb, int bi) {
        const int sweeps = (cb + 15) >> 4;     // 16 edge rows per sweep
        for (int j = 0; j < sweeps; ++j) {
            int sl  = j * 16 + (lane >> 2);
            int eid = __shfl(prv.y, sl);
            if (sl >= cb) eid = 0;             // clamped, harmless in-bounds
            const float* gp = ea + (size_t)eid * 16 + (lane & 3) * 4;
            __builtin_amdgcn_global_load_lds(gp, &sEA[w][bi][j * 16][0], 16, 0, 0);
        }
    };

    auto COMPUTE = [&](const float4& E0, const float4& E1,
                       const float4& E2, const float4& E3, const XT& X) {
        f32x2 ap[8] = {f32x2{E0.x, E0.y}, f32x2{E0.z, E0.w},
                       f32x2{E1.x, E1.y}, f32x2{E1.z, E1.w},
                       f32x2{E2.x, E2.y}, f32x2{E2.z, E2.w},
                       f32x2{E3.x, E3.y}, f32x2{E3.z, E3.w}};
        f32x2 m[NP];
        if constexpr (XB) {
            m[0] = pk_add(bx[0], f32x2{b2f(X.x), b2f(X.y)});
            m[1] = pk_add(bx[1], f32x2{b2f(X.z), b2f(X.w)});
        } else if constexpr (NP == 1) {
            m[0] = pk_add(bx[0], f32x2{X.x, X.y});
        } else {
            m[0] = pk_add(bx[0], f32x2{X.x, X.y});
            m[1] = pk_add(bx[1], f32x2{X.z, X.w});
        }
#pragma unroll
        for (int kp = 0; kp < 8; ++kp) {
#pragma unroll
            for (int p = 0; p < NP; ++p)
                m[p] = pk_fma_lo(ap[kp], wrp[(2 * kp) * NP + p], m[p]);
#pragma unroll
            for (int p = 0; p < NP; ++p)
                m[p] = pk_fma_hi(ap[kp], wrp[(2 * kp + 1) * NP + p], m[p]);
        }
#pragma unroll
        for (int p = 0; p < NP; ++p) {
            f32x2 r{fmaxf(m[p].x, 0.f), fmaxf(m[p].y, 0.f)};
            acc[p] = pk_add(acc[p], r);
        }
    };

    // compute one staged batch from LDS buffer bi; srcs broadcast from prv.x
    auto RUN = [&](int cb, int bi, int2 prv) {
        if (cb <= 0) return;
        float4 EA0, EA1, EA2, EA3, EB0, EB1, EB2, EB3;
        XT xA, xB;
        auto LA = [&](int i) {
            const float4* rp = reinterpret_cast<const float4*>(&sEA[w][bi][i][0]);
            EA0 = rp[0]; EA1 = rp[1]; EA2 = rp[2]; EA3 = rp[3];
            int s = __builtin_amdgcn_readlane(prv.x, i);
            if constexpr (XB) xA = *reinterpret_cast<const XT*>(xb + (size_t)s * D + d0);
            else              xA = *reinterpret_cast<const XT*>(xf + (size_t)s * D + d0);
        };
        auto LB = [&](int i) {
            const float4* rp = reinterpret_cast<const float4*>(&sEA[w][bi][i][0]);
            EB0 = rp[0]; EB1 = rp[1]; EB2 = rp[2]; EB3 = rp[3];
            int s = __builtin_amdgcn_readlane(prv.x, i);
            if constexpr (XB) xB = *reinterpret_cast<const XT*>(xb + (size_t)s * D + d0);
            else              xB = *reinterpret_cast<const XT*>(xf + (size_t)s * D + d0);
        };
        LA(0);
        int i = 0;
        while (true) {
            if (i + 1 < cb) LB(i + 1);
            COMPUTE(EA0, EA1, EA2, EA3, xA);
            ++i; if (i >= cb) break;
            if (i + 1 < cb) LA(i + 1);
            COMPUTE(EB0, EB1, EB2, EB3, xB);
            ++i; if (i >= cb) break;
        }
    };

    // ---- prologue: first batch's edge list + staging, one drain
    int cb0 = min(c, 64);
    int2 pr = make_int2(0, 0);
    if (lane < cb0) pr = sorted2[s0 + lane];
    STAGE(pr, cb0, 0);
    asm volatile("s_waitcnt vmcnt(0)" ::: "memory");

    int buf = 0, base = 0;
    while (true) {
        const int cc = min(64, c - base);
        const int nbase = base + 64;
        int2 prn = make_int2(0, 0);
        int ccn = 0;
        if (nbase < c) {                       // rare: degree > 64
            ccn = min(64, c - nbase);
            if (lane < ccn) prn = sorted2[s0 + nbase + lane];
            STAGE(prn, ccn, buf ^ 1);          // issued BEFORE compute
        }
        RUN(cc, buf, pr);
        if (nbase >= c) break;
        asm volatile("s_waitcnt vmcnt(0)" ::: "memory");
        pr = prn; base = nbase; buf ^= 1;
    }

    if constexpr (NP == 1)
        *reinterpret_cast<float2*>(agg + (size_t)node * D + d0) =
            make_float2(acc[0].x, acc[0].y);
    else
        *reinterpret_cast<float4*>(agg + (size_t)node * D + d0) =
            make_float4(acc[0].x, acc[0].y, acc[1].x, acc[1].y);
}

// ---------------------------------------------------------------------------
// Fused node MLP via MFMA bf16 (unchanged)
// ---------------------------------------------------------------------------
template<int DIN, bool L1>
__global__ __launch_bounds__(256) void node_mfma_kernel(
    const float*          __restrict__ basef,
    const unsigned short* __restrict__ baseb,
    const float*          __restrict__ agg,
    const unsigned short* __restrict__ w1T,
    const float*          __restrict__ b1,
    const unsigned short* __restrict__ w2T,
    const float*          __restrict__ b2,
    unsigned short*       __restrict__ outb,
    float*                __restrict__ outf,
    int N)
{
    __shared__ unsigned short hs[64 * DIN];
    __shared__ unsigned short ts[64 * 256];
    const int tid = threadIdx.x;
    const int n0 = blockIdx.x * 64;

#pragma unroll
    for (int it = 0; it < (64 * DIN) / (256 * 8); ++it) {
        int flat = (it * 256 + tid) * 8;
        int r = flat / DIN, c = flat % DIN;
        int node = n0 + r;
        float v[8];
        if (node < N) {
            const float* ap = agg + (size_t)node * DIN + c;
            float4 a0 = *reinterpret_cast<const float4*>(ap);
            float4 a1 = *reinterpret_cast<const float4*>(ap + 4);
            float a[8] = {a0.x, a0.y, a0.z, a0.w, a1.x, a1.y, a1.z, a1.w};
            if constexpr (L1) {
                const float* bp = basef + (size_t)node * DIN + c;
                float4 x0 = *reinterpret_cast<const float4*>(bp);
                float4 x1 = *reinterpret_cast<const float4*>(bp + 4);
                float xx[8] = {x0.x, x0.y, x0.z, x0.w, x1.x, x1.y, x1.z, x1.w};
#pragma unroll
                for (int j = 0; j < 8; ++j) v[j] = a[j] + xx[j];
            } else {
                short8 xv = *reinterpret_cast<const short8*>(baseb + (size_t)node * DIN + c);
#pragma unroll
                for (int j = 0; j < 8; ++j) v[j] = a[j] + b2f((unsigned short)xv[j]);
            }
        } else {
#pragma unroll
            for (int j = 0; j < 8; ++j) v[j] = 0.f;
        }
        short8 o;
#pragma unroll
        for (int j = 0; j < 8; ++j) o[j] = (short)f2b(v[j]);
        *reinterpret_cast<short8*>(&hs[r * DIN + (c ^ ((r & 7) << 3))]) = o;
    }
    __syncthreads();

    const int wv = tid >> 6, lane = tid & 63;
    const int lr = lane & 15, lk = (lane >> 4) * 8;
    const int colbase = wv * 64;

    floatx4 acc[4][4];
#pragma unroll
    for (int n = 0; n < 4; ++n) {
        float bn = b1[colbase + n * 16 + lr];
#pragma unroll
        for (int m = 0; m < 4; ++m) acc[m][n] = floatx4{bn, bn, bn, bn};
    }
#pragma unroll
    for (int kk = 0; kk < DIN; kk += 32) {
        short8 af[4], bf[4];
#pragma unroll
        for (int m = 0; m < 4; ++m) {
            int row = m * 16 + lr;
            af[m] = *reinterpret_cast<const short8*>(
                &hs[row * DIN + ((kk + lk) ^ ((row & 7) << 3))]);
        }
#pragma unroll
        for (int n = 0; n < 4; ++n) {
            int col = colbase + n * 16 + lr;
            bf[n] = *reinterpret_cast<const short8*>(w1T + (size_t)col * DIN + kk + lk);
        }
#pragma unroll
        for (int m = 0; m < 4; ++m)
#pragma unroll
            for (int n = 0; n < 4; ++n)
                acc[m][n] = __builtin_amdgcn_mfma_f32_16x16x32_bf16(af[m], bf[n], acc[m][n], 0, 0, 0);
    }
#pragma unroll
    for (int m = 0; m < 4; ++m)
#pragma unroll
        for (int n = 0; n < 4; ++n)
#pragma unroll
            for (int r = 0; r < 4; ++r) {
                int row = m * 16 + (lane >> 4) * 4 + r;
                int col = colbase + n * 16 + lr;
                ts[row * 256 + (col ^ ((row & 7) << 3))] = f2b(fmaxf(acc[m][n][r], 0.f));
            }
    __syncthreads();

    floatx4 acc2[4][4];
#pragma unroll
    for (int n = 0; n < 4; ++n) {
        float bn = b2[colbase + n * 16 + lr];
#pragma unroll
        for (int m = 0; m < 4; ++m) acc2[m][n] = floatx4{bn, bn, bn, bn};
    }
#pragma unroll
    for (int kk = 0; kk < 256; kk += 32) {
        short8 af[4], bf[4];
#pragma unroll
        for (int m = 0; m < 4; ++m) {
            int row = m * 16 + lr;
            af[m] = *reinterpret_cast<const short8*>(
                &ts[row * 256 + ((kk + lk) ^ ((row & 7) << 3))]);
        }
#pragma unroll
        for (int n = 0; n < 4; ++n) {
            int col = colbase + n * 16 + lr;
            bf[n] = *reinterpret_cast<const short8*>(w2T + (size_t)col * 256 + kk + lk);
        }
#pragma unroll
        for (int m = 0; m < 4; ++m)
#pragma unroll
            for (int n = 0; n < 4; ++n)
                acc2[m][n] = __builtin_amdgcn_mfma_f32_16x16x32_bf16(af[m], bf[n], acc2[m][n], 0, 0, 0);
    }
#pragma unroll
    for (int m = 0; m < 4; ++m)
#pragma unroll
        for (int n = 0; n < 4; ++n)
#pragma unroll
            for (int r = 0; r < 4; ++r) {
                int row = m * 16 + (lane >> 4) * 4 + r;
                int node = n0 + row;
                int col = colbase + n * 16 + lr;
                if (node < N) {
                    if constexpr (L1) outb[(size_t)node * 256 + col] = f2b(acc2[m][n][r]);
                    else              outf[(size_t)node * 256 + col] = acc2[m][n][r];
                }
            }
}

// ---------------------------------------------------------------------------
extern "C" void kernel_launch(void* const* d_in, const int* in_sizes, int n_in,
                              void* d_out, int out_size, void* d_ws, size_t ws_size,
                              hipStream_t stream)
{
    const float* x    = (const float*)d_in[0];
    const int*   ei   = (const int*)  d_in[1];
    const float* ea   = (const float*)d_in[2];
    const float* e1w  = (const float*)d_in[3];
    const float* e1b  = (const float*)d_in[4];
    const float* w11  = (const float*)d_in[5];
    const float* b11  = (const float*)d_in[6];
    const float* w12  = (const float*)d_in[7];
    const float* b12  = (const float*)d_in[8];
    const float* e2w  = (const float*)d_in[9];
    const float* e2b  = (const float*)d_in[10];
    const float* w21  = (const float*)d_in[11];
    const float* b21  = (const float*)d_in[12];
    const float* w22  = (const float*)d_in[13];
    const float* b22  = (const float*)d_in[14];

    const int E = in_sizes[1] / 2;
    const int N = N_NODES;
    const int* src = ei;
    const int* dst = ei + E;

    // ---- workspace layout
    char* cur = (char*)d_ws;
    float* aggb = (float*)cur;            cur += (size_t)N * 256 * 4;
    int*   cnt       = (int*)cur;         cur += (size_t)N * 4;
    int*   row_start = (int*)cur;         cur += (size_t)N * 4;
    int*   woff      = (int*)cur;         cur += (size_t)N * 4;
    int*   bsum      = (int*)cur;         cur += 256 * 4;
    int2*  sorted2   = (int2*)cur;        cur += (size_t)E * 8;
    unsigned short* h1b  = (unsigned short*)cur; cur += (size_t)N * 256 * 2;
    unsigned short* w11T = (unsigned short*)cur; cur += 128 * 256 * 2;
    unsigned short* w12T = (unsigned short*)cur; cur += 256 * 256 * 2;
    unsigned short* w21T = (unsigned short*)cur; cur += 256 * 256 * 2;
    unsigned short* w22T = (unsigned short*)cur; cur += 256 * 256 * 2;
    float* outp = (float*)d_out;

    const int nbN = (N + 255) / 256;
    const int nbE = (E + 255) / 256;

    // ---- weight casts
    castT_kernel<<<(128 * 256 + 255) / 256, 256, 0, stream>>>(w11, w11T, 128);
    castT_kernel<<<256, 256, 0, stream>>>(w12, w12T, 256);
    castT_kernel<<<256, 256, 0, stream>>>(w21, w21T, 256);
    castT_kernel<<<256, 256, 0, stream>>>(w22, w22T, 256);

    // ---- CSR build (shared by both layers)
    zero_int_kernel<<<nbN, 256, 0, stream>>>(cnt, N);
    hist_kernel<<<nbE, 256, 0, stream>>>(dst, cnt, E);
    scanA_kernel<<<nbN, 256, 0, stream>>>(cnt, row_start, bsum, N);
    scanB_kernel<<<1, 256, 0, stream>>>(bsum, nbN);
    scanC_kernel<<<nbN, 256, 0, stream>>>(row_start, woff, bsum, N);
    scatter_kernel<<<nbE, 256, 0, stream>>>(src, dst, woff, sorted2, E);

    const int nbAgg  = (N + 3) / 4;
    const int nbNode = (N + 63) / 64;

    // ---- layer 1
    agg_kernel<128, false><<<nbAgg, 256, 0, stream>>>(
        x, nullptr, ea, e1w, e1b, row_start, cnt, sorted2, aggb, N);
    node_mfma_kernel<128, true><<<nbNode, 256, 0, stream>>>(
        x, nullptr, aggb, w11T, b11, w12T, b12, h1b, nullptr, N);

    // ---- layer 2
    agg_kernel<256, true><<<nbAgg, 256, 0, stream>>>(
        nullptr, h1b, ea, e2w, e2b, row_start, cnt, sorted2, aggb, N);
    node_mfma_kernel<256, false><<<nbNode, 256, 0, stream>>>(
        nullptr, h1b, aggb, w21T, b21, w22T, b22, nullptr, outp, N);
}

// Round 7
// 405.273 us; speedup vs baseline: 1.2738x; 1.2738x over previous
//
#include <hip/hip_runtime.h>
#include <type_traits>

#define N_NODES 50000

using short8  = __attribute__((ext_vector_type(8))) short;
using floatx4 = __attribute__((ext_vector_type(4))) float;
using f32x2   = __attribute__((ext_vector_type(2))) float;

__device__ inline unsigned short f2b(float f) {
    unsigned u = __float_as_uint(f);
    u += 0x7FFFu + ((u >> 16) & 1u);           // RNE
    return (unsigned short)(u >> 16);
}
__device__ inline float b2f(unsigned short h) {
    return __uint_as_float(((unsigned)h) << 16);
}

// ---------------------------------------------------------------------------
// Edge-lin math in PLAIN C vector ops (no inline asm!).
//
// Rounds 0-6 fed v_pk_fma_f32 via asm with "v" constraints. That constraint
// forces every operand into an arch VGPR at every use; the allocator parks
// the 64-reg weight slice in the AGPR side of the unified file and emits
// v_accvgpr_read copies PER WEIGHT OPERAND PER EDGE (~32/edge) to satisfy
// the asm — the measured ~2.4x VALU-issue bloat (218M cyc observed vs ~90M
// useful in the agg<256> window). Plain VALU instrs can read AGPRs
// directly, but only when the COMPILER emits them. These builtins produce
// the same FMA dag (bit-identical results) and let the backend pick
// v_pk_fma_f32 / operand locations itself.
// ---------------------------------------------------------------------------
__device__ inline f32x2 splat2(float v)            { return f32x2{v, v}; }
__device__ inline f32x2 vfma(f32x2 a, f32x2 b, f32x2 c) {
    return __builtin_elementwise_fma(a, b, c);
}
__device__ inline f32x2 vrelu(f32x2 a) {
    return __builtin_elementwise_max(a, f32x2{0.f, 0.f});
}

// ---------------------------------------------------------------------------
// CSR build
// ---------------------------------------------------------------------------
__global__ __launch_bounds__(256) void zero_int_kernel(int* __restrict__ p, int n)
{
    int i = blockIdx.x * 256 + threadIdx.x;
    if (i < n) p[i] = 0;
}

__global__ __launch_bounds__(256) void hist_kernel(const int* __restrict__ dstv,
                                                   int* __restrict__ cnt, int E)
{
    int e = blockIdx.x * 256 + threadIdx.x;
    if (e < E) atomicAdd(&cnt[dstv[e]], 1);
}

__global__ __launch_bounds__(256) void scanA_kernel(const int* __restrict__ cnt,
                                                    int* __restrict__ row_start,
                                                    int* __restrict__ bsum, int n)
{
    __shared__ int s[256];
    int t = threadIdx.x;
    int i = blockIdx.x * 256 + t;
    int val = (i < n) ? cnt[i] : 0;
    s[t] = val;
    __syncthreads();
#pragma unroll
    for (int off = 1; off < 256; off <<= 1) {
        int v = (t >= off) ? s[t - off] : 0;
        __syncthreads();
        s[t] += v;
        __syncthreads();
    }
    if (i < n) row_start[i] = s[t] - val;
    if (t == 255) bsum[blockIdx.x] = s[255];
}

__global__ __launch_bounds__(256) void scanB_kernel(int* __restrict__ bsum, int nb)
{
    __shared__ int s[256];
    int t = threadIdx.x;
    int val = (t < nb) ? bsum[t] : 0;
    s[t] = val;
    __syncthreads();
#pragma unroll
    for (int off = 1; off < 256; off <<= 1) {
        int v = (t >= off) ? s[t - off] : 0;
        __syncthreads();
        s[t] += v;
        __syncthreads();
    }
    if (t < nb) bsum[t] = s[t] - val;
}

__global__ __launch_bounds__(256) void scanC_kernel(int* __restrict__ row_start,
                                                    int* __restrict__ woff,
                                                    const int* __restrict__ bsum, int n)
{
    int i = blockIdx.x * 256 + threadIdx.x;
    if (i < n) {
        int v = row_start[i] + bsum[blockIdx.x];
        row_start[i] = v;
        woff[i] = v;
    }
}

__global__ __launch_bounds__(256) void scatter_kernel(const int* __restrict__ srcv,
                                                      const int* __restrict__ dstv,
                                                      int* __restrict__ woff,
                                                      int2* __restrict__ sorted2, int E)
{
    int e = blockIdx.x * 256 + threadIdx.x;
    if (e < E) {
        int pos = atomicAdd(&woff[dstv[e]], 1);
        sorted2[pos] = make_int2(srcv[e], e);
    }
}

// ---------------------------------------------------------------------------
// Weight cast+transpose: w [K,256] f32 -> wT [256][K] bf16
// ---------------------------------------------------------------------------
__global__ __launch_bounds__(256) void castT_kernel(const float* __restrict__ w,
                                                    unsigned short* __restrict__ out, int K)
{
    int i = blockIdx.x * 256 + threadIdx.x;
    if (i < K * 256) {
        int k = i >> 8, c = i & 255;
        out[c * K + k] = f2b(w[i]);
    }
}

// ---------------------------------------------------------------------------
// Gather aggregation, one wave per node (round-0 topology, best measured).
// Edge (src,eid) pairs cooperatively loaded 64 at a time, broadcast via
// v_readlane. Per-edge ea/x loads ping-pong double-buffered. Edge-lin math
// in plain C vector FMA (see note above) — the ONLY change vs round 0.
// ---------------------------------------------------------------------------
template<int D, bool XB>
__global__ __launch_bounds__(256) void agg_kernel(
    const float*          __restrict__ xf,
    const unsigned short* __restrict__ xb,
    const float*          __restrict__ ea,     // [E, 16]
    const float*          __restrict__ ew,     // [16, D]
    const float*          __restrict__ ebias,  // [D]
    const int*            __restrict__ row_start,
    const int*            __restrict__ cnt,
    const int2*           __restrict__ sorted2, // [E] {src, eid}
    float*                __restrict__ agg,    // [N, D]
    int N)
{
    constexpr int DPL = D / 64;     // dims per lane
    constexpr int NP  = DPL / 2;    // f32x2 pairs per lane
    using XT = std::conditional_t<XB, ushort4,
               std::conditional_t<DPL == 2, float2, float4>>;

    const int lane = threadIdx.x & 63;
    const int node = blockIdx.x * 4 + (threadIdx.x >> 6);
    if (node >= N) return;
    const int d0 = lane * DPL;

    f32x2 wrp[16 * NP];
#pragma unroll
    for (int k = 0; k < 16; ++k) {
        if constexpr (NP == 1) {
            float2 w2 = *reinterpret_cast<const float2*>(ew + k * D + d0);
            wrp[k] = f32x2{w2.x, w2.y};
        } else {
            float4 w4 = *reinterpret_cast<const float4*>(ew + k * D + d0);
            wrp[k * 2 + 0] = f32x2{w4.x, w4.y};
            wrp[k * 2 + 1] = f32x2{w4.z, w4.w};
        }
    }
    f32x2 bx[NP];
#pragma unroll
    for (int p = 0; p < NP; ++p)
        bx[p] = f32x2{ebias[d0 + p * 2], ebias[d0 + p * 2 + 1]};

    f32x2 acc[NP];
#pragma unroll
    for (int p = 0; p < NP; ++p) acc[p] = f32x2{0.f, 0.f};

    const int s0 = __builtin_amdgcn_readfirstlane(row_start[node]);
    const int c  = __builtin_amdgcn_readfirstlane(cnt[node]);

    for (int base = 0; base < c; base += 64) {
        const int cc = min(64, c - base);

        int2 pr = make_int2(0, 0);
        if (lane < cc) pr = sorted2[s0 + base + lane];

        float4 eA0, eA1, eA2, eA3; XT xA;
        float4 eB0, eB1, eB2, eB3; XT xB;

        auto LOADA = [&](int idx) {
            int s = __builtin_amdgcn_readlane(pr.x, idx);
            int e = __builtin_amdgcn_readlane(pr.y, idx);
            const float4* p = reinterpret_cast<const float4*>(ea + (size_t)e * 16);
            eA0 = p[0]; eA1 = p[1]; eA2 = p[2]; eA3 = p[3];
            if constexpr (XB) xA = *reinterpret_cast<const XT*>(xb + (size_t)s * D + d0);
            else              xA = *reinterpret_cast<const XT*>(xf + (size_t)s * D + d0);
        };
        auto LOADB = [&](int idx) {
            int s = __builtin_amdgcn_readlane(pr.x, idx);
            int e = __builtin_amdgcn_readlane(pr.y, idx);
            const float4* p = reinterpret_cast<const float4*>(ea + (size_t)e * 16);
            eB0 = p[0]; eB1 = p[1]; eB2 = p[2]; eB3 = p[3];
            if constexpr (XB) xB = *reinterpret_cast<const XT*>(xb + (size_t)s * D + d0);
            else              xB = *reinterpret_cast<const XT*>(xf + (size_t)s * D + d0);
        };

        auto COMPUTE = [&](const float4& E0, const float4& E1,
                           const float4& E2, const float4& E3, const XT& X) {
            float av[16] = {E0.x, E0.y, E0.z, E0.w,
                            E1.x, E1.y, E1.z, E1.w,
                            E2.x, E2.y, E2.z, E2.w,
                            E3.x, E3.y, E3.z, E3.w};
            f32x2 m[NP];
            if constexpr (XB) {
                m[0] = bx[0] + f32x2{b2f(X.x), b2f(X.y)};
                m[1] = bx[1] + f32x2{b2f(X.z), b2f(X.w)};
            } else if constexpr (NP == 1) {
                m[0] = bx[0] + f32x2{X.x, X.y};
            } else {
                m[0] = bx[0] + f32x2{X.x, X.y};
                m[1] = bx[1] + f32x2{X.z, X.w};
            }
#pragma unroll
            for (int k = 0; k < 16; ++k) {
                f32x2 a = splat2(av[k]);
#pragma unroll
                for (int p = 0; p < NP; ++p)
                    m[p] = vfma(a, wrp[k * NP + p], m[p]);
            }
#pragma unroll
            for (int p = 0; p < NP; ++p)
                acc[p] = acc[p] + vrelu(m[p]);
        };

        LOADA(0);
        int i = 0;
        while (true) {
            if (i + 1 < cc) LOADB(i + 1);
            COMPUTE(eA0, eA1, eA2, eA3, xA);
            ++i; if (i >= cc) break;
            if (i + 1 < cc) LOADA(i + 1);
            COMPUTE(eB0, eB1, eB2, eB3, xB);
            ++i; if (i >= cc) break;
        }
    }

    if constexpr (NP == 1)
        *reinterpret_cast<float2*>(agg + (size_t)node * D + d0) =
            make_float2(acc[0].x, acc[0].y);
    else
        *reinterpret_cast<float4*>(agg + (size_t)node * D + d0) =
            make_float4(acc[0].x, acc[0].y, acc[1].x, acc[1].y);
}

// ---------------------------------------------------------------------------
// Fused node MLP via MFMA bf16 (unchanged)
// ---------------------------------------------------------------------------
template<int DIN, bool L1>
__global__ __launch_bounds__(256) void node_mfma_kernel(
    const float*          __restrict__ basef,
    const unsigned short* __restrict__ baseb,
    const float*          __restrict__ agg,
    const unsigned short* __restrict__ w1T,
    const float*          __restrict__ b1,
    const unsigned short* __restrict__ w2T,
    const float*          __restrict__ b2,
    unsigned short*       __restrict__ outb,
    float*                __restrict__ outf,
    int N)
{
    __shared__ unsigned short hs[64 * DIN];
    __shared__ unsigned short ts[64 * 256];
    const int tid = threadIdx.x;
    const int n0 = blockIdx.x * 64;

#pragma unroll
    for (int it = 0; it < (64 * DIN) / (256 * 8); ++it) {
        int flat = (it * 256 + tid) * 8;
        int r = flat / DIN, c = flat % DIN;
        int node = n0 + r;
        float v[8];
        if (node < N) {
            const float* ap = agg + (size_t)node * DIN + c;
            float4 a0 = *reinterpret_cast<const float4*>(ap);
            float4 a1 = *reinterpret_cast<const float4*>(ap + 4);
            float a[8] = {a0.x, a0.y, a0.z, a0.w, a1.x, a1.y, a1.z, a1.w};
            if constexpr (L1) {
                const float* bp = basef + (size_t)node * DIN + c;
                float4 x0 = *reinterpret_cast<const float4*>(bp);
                float4 x1 = *reinterpret_cast<const float4*>(bp + 4);
                float xx[8] = {x0.x, x0.y, x0.z, x0.w, x1.x, x1.y, x1.z, x1.w};
#pragma unroll
                for (int j = 0; j < 8; ++j) v[j] = a[j] + xx[j];
            } else {
                short8 xv = *reinterpret_cast<const short8*>(baseb + (size_t)node * DIN + c);
#pragma unroll
                for (int j = 0; j < 8; ++j) v[j] = a[j] + b2f((unsigned short)xv[j]);
            }
        } else {
#pragma unroll
            for (int j = 0; j < 8; ++j) v[j] = 0.f;
        }
        short8 o;
#pragma unroll
        for (int j = 0; j < 8; ++j) o[j] = (short)f2b(v[j]);
        *reinterpret_cast<short8*>(&hs[r * DIN + (c ^ ((r & 7) << 3))]) = o;
    }
    __syncthreads();

    const int wv = tid >> 6, lane = tid & 63;
    const int lr = lane & 15, lk = (lane >> 4) * 8;
    const int colbase = wv * 64;

    floatx4 acc[4][4];
#pragma unroll
    for (int n = 0; n < 4; ++n) {
        float bn = b1[colbase + n * 16 + lr];
#pragma unroll
        for (int m = 0; m < 4; ++m) acc[m][n] = floatx4{bn, bn, bn, bn};
    }
#pragma unroll
    for (int kk = 0; kk < DIN; kk += 32) {
        short8 af[4], bf[4];
#pragma unroll
        for (int m = 0; m < 4; ++m) {
            int row = m * 16 + lr;
            af[m] = *reinterpret_cast<const short8*>(
                &hs[row * DIN + ((kk + lk) ^ ((row & 7) << 3))]);
        }
#pragma unroll
        for (int n = 0; n < 4; ++n) {
            int col = colbase + n * 16 + lr;
            bf[n] = *reinterpret_cast<const short8*>(w1T + (size_t)col * DIN + kk + lk);
        }
#pragma unroll
        for (int m = 0; m < 4; ++m)
#pragma unroll
            for (int n = 0; n < 4; ++n)
                acc[m][n] = __builtin_amdgcn_mfma_f32_16x16x32_bf16(af[m], bf[n], acc[m][n], 0, 0, 0);
    }
#pragma unroll
    for (int m = 0; m < 4; ++m)
#pragma unroll
        for (int n = 0; n < 4; ++n)
#pragma unroll
            for (int r = 0; r < 4; ++r) {
                int row = m * 16 + (lane >> 4) * 4 + r;
                int col = colbase + n * 16 + lr;
                ts[row * 256 + (col ^ ((row & 7) << 3))] = f2b(fmaxf(acc[m][n][r], 0.f));
            }
    __syncthreads();

    floatx4 acc2[4][4];
#pragma unroll
    for (int n = 0; n < 4; ++n) {
        float bn = b2[colbase + n * 16 + lr];
#pragma unroll
        for (int m = 0; m < 4; ++m) acc2[m][n] = floatx4{bn, bn, bn, bn};
    }
#pragma unroll
    for (int kk = 0; kk < 256; kk += 32) {
        short8 af[4], bf[4];
#pragma unroll
        for (int m = 0; m < 4; ++m) {
            int row = m * 16 + lr;
            af[m] = *reinterpret_cast<const short8*>(
                &ts[row * 256 + ((kk + lk) ^ ((row & 7) << 3))]);
        }
#pragma unroll
        for (int n = 0; n < 4; ++n) {
            int col = colbase + n * 16 + lr;
            bf[n] = *reinterpret_cast<const short8*>(w2T + (size_t)col * 256 + kk + lk);
        }
#pragma unroll
        for (int m = 0; m < 4; ++m)
#pragma unroll
            for (int n = 0; n < 4; ++n)
                acc2[m][n] = __builtin_amdgcn_mfma_f32_16x16x32_bf16(af[m], bf[n], acc2[m][n], 0, 0, 0);
    }
#pragma unroll
    for (int m = 0; m < 4; ++m)
#pragma unroll
        for (int n = 0; n < 4; ++n)
#pragma unroll
            for (int r = 0; r < 4; ++r) {
                int row = m * 16 + (lane >> 4) * 4 + r;
                int node = n0 + row;
                int col = colbase + n * 16 + lr;
                if (node < N) {
                    if constexpr (L1) outb[(size_t)node * 256 + col] = f2b(acc2[m][n][r]);
                    else              outf[(size_t)node * 256 + col] = acc2[m][n][r];
                }
            }
}

// ---------------------------------------------------------------------------
extern "C" void kernel_launch(void* const* d_in, const int* in_sizes, int n_in,
                              void* d_out, int out_size, void* d_ws, size_t ws_size,
                              hipStream_t stream)
{
    const float* x    = (const float*)d_in[0];
    const int*   ei   = (const int*)  d_in[1];
    const float* ea   = (const float*)d_in[2];
    const float* e1w  = (const float*)d_in[3];
    const float* e1b  = (const float*)d_in[4];
    const float* w11  = (const float*)d_in[5];
    const float* b11  = (const float*)d_in[6];
    const float* w12  = (const float*)d_in[7];
    const float* b12  = (const float*)d_in[8];
    const float* e2w  = (const float*)d_in[9];
    const float* e2b  = (const float*)d_in[10];
    const float* w21  = (const float*)d_in[11];
    const float* b21  = (const float*)d_in[12];
    const float* w22  = (const float*)d_in[13];
    const float* b22  = (const float*)d_in[14];

    const int E = in_sizes[1] / 2;
    const int N = N_NODES;
    const int* src = ei;
    const int* dst = ei + E;

    // ---- workspace layout
    char* cur = (char*)d_ws;
    float* aggb = (float*)cur;            cur += (size_t)N * 256 * 4;
    int*   cnt       = (int*)cur;         cur += (size_t)N * 4;
    int*   row_start = (int*)cur;         cur += (size_t)N * 4;
    int*   woff      = (int*)cur;         cur += (size_t)N * 4;
    int*   bsum      = (int*)cur;         cur += 256 * 4;
    int2*  sorted2   = (int2*)cur;        cur += (size_t)E * 8;
    unsigned short* h1b  = (unsigned short*)cur; cur += (size_t)N * 256 * 2;
    unsigned short* w11T = (unsigned short*)cur; cur += 128 * 256 * 2;
    unsigned short* w12T = (unsigned short*)cur; cur += 256 * 256 * 2;
    unsigned short* w21T = (unsigned short*)cur; cur += 256 * 256 * 2;
    unsigned short* w22T = (unsigned short*)cur; cur += 256 * 256 * 2;
    float* outp = (float*)d_out;

    const int nbN = (N + 255) / 256;
    const int nbE = (E + 255) / 256;

    // ---- weight casts
    castT_kernel<<<(128 * 256 + 255) / 256, 256, 0, stream>>>(w11, w11T, 128);
    castT_kernel<<<256, 256, 0, stream>>>(w12, w12T, 256);
    castT_kernel<<<256, 256, 0, stream>>>(w21, w21T, 256);
    castT_kernel<<<256, 256, 0, stream>>>(w22, w22T, 256);

    // ---- CSR build (shared by both layers)
    zero_int_kernel<<<nbN, 256, 0, stream>>>(cnt, N);
    hist_kernel<<<nbE, 256, 0, stream>>>(dst, cnt, E);
    scanA_kernel<<<nbN, 256, 0, stream>>>(cnt, row_start, bsum, N);
    scanB_kernel<<<1, 256, 0, stream>>>(bsum, nbN);
    scanC_kernel<<<nbN, 256, 0, stream>>>(row_start, woff, bsum, N);
    scatter_kernel<<<nbE, 256, 0, stream>>>(src, dst, woff, sorted2, E);

    const int nbAgg  = (N + 3) / 4;
    const int nbNode = (N + 63) / 64;

    // ---- layer 1
    agg_kernel<128, false><<<nbAgg, 256, 0, stream>>>(
        x, nullptr, ea, e1w, e1b, row_start, cnt, sorted2, aggb, N);
    node_mfma_kernel<128, true><<<nbNode, 256, 0, stream>>>(
        x, nullptr, aggb, w11T, b11, w12T, b12, h1b, nullptr, N);

    // ---- layer 2
    agg_kernel<256, true><<<nbAgg, 256, 0, stream>>>(
        nullptr, h1b, ea, e2w, e2b, row_start, cnt, sorted2, aggb, N);
    node_mfma_kernel<256, false><<<nbNode, 256, 0, stream>>>(
        nullptr, h1b, aggb, w21T, b21, w22T, b22, nullptr, outp, N);
}